// Round 7
// baseline (1195.963 us; speedup 1.0000x reference)
//
#include <hip/hip_runtime.h>
#include <stdint.h>

// Problem constants (fixed by setup_inputs)
#define TOKENS 64
#define IN_F   4096
#define OUT_F  11008
#define RANK   16
#define GS     128
#define NG     32
#define ZCOLS  (OUT_F / 8)
#define LORA_SCALE 2.0f

// DIAGNOSTIC ROUND: repeat main x16 and prep x64 (opaque-zero defeats LICM)
// so they enter rocprof's top-5 and expose per-kernel counters. Results are
// numerically identical (idempotent prep; main acc scaled by exact 1/16).
#define REP_MAIN 16
#define REP_PREP 64

using short8  = __attribute__((ext_vector_type(8))) short;
using float4v = __attribute__((ext_vector_type(4))) float;

// round-to-nearest-even fp32 -> bf16 bits; also returns the rounded-back fp32
static __device__ inline uint16_t f2bf(float f, float* back) {
    uint32_t u = __float_as_uint(f);
    uint32_t r = (u + 0x7FFFu + ((u >> 16) & 1u)) >> 16;
    *back = __uint_as_float(r << 16);
    return (uint16_t)r;
}

// ---------------------------------------------------------------------------
// K1: per token t (64 blocks):
//   xf (MFMA-fragment order) = bf16(x)  — xf4[(mt*128 + kchunk)*64 + quad*16 + n]
//   xsumT[g][t] = sum over group g of bf16-rounded x   (GPTQ zero fold)
//   midT[j][t]  = sum_k x[t][k] * lora_A[j][k]         (fp32 LoRA mid)
// ---------------------------------------------------------------------------
__global__ __launch_bounds__(256) void prep_kernel(
        const float* __restrict__ x,
        const float* __restrict__ loraA,
        uint4* __restrict__ xf4,
        float* __restrict__ xsumT,
        float* __restrict__ midT) {
    __shared__ float redg[256];
    __shared__ float redm[4][16];
    const int t    = blockIdx.x;
    const int tid  = threadIdx.x;
    const int lane = tid & 63;
    const int wv   = tid >> 6;

    #pragma unroll 1
    for (int rep = 0; rep < REP_PREP; ++rep) {
        int zero;
        asm volatile("v_mov_b32 %0, 0" : "=v"(zero));   // opaque 0: no LICM
        const float* x_l     = x + zero;
        const float* loraA_l = loraA + zero;

        __syncthreads();   // protect redg/redm across reps

        float4 xv[4];
        const float4* xp = (const float4*)(x_l + (size_t)t * IN_F + tid * 16);
        #pragma unroll
        for (int i = 0; i < 4; ++i) xv[i] = xp[i];

        union { uint16_t u[16]; uint4 q[2]; } ob;
        float s = 0.f;
        #pragma unroll
        for (int i = 0; i < 4; ++i) {
            float b;
            ob.u[i * 4 + 0] = f2bf(xv[i].x, &b); s += b;
            ob.u[i * 4 + 1] = f2bf(xv[i].y, &b); s += b;
            ob.u[i * 4 + 2] = f2bf(xv[i].z, &b); s += b;
            ob.u[i * 4 + 3] = f2bf(xv[i].w, &b); s += b;
        }
        // scatter into fragment order (idempotent across reps)
        {
            const int mm = t >> 4, nn = t & 15;
            const int kchunk = tid >> 1;
            #pragma unroll
            for (int i = 0; i < 2; ++i) {
                const int qd = (tid * 2 + i) & 3;
                xf4[(size_t)((mm * 128 + kchunk) * 64 + qd * 16 + nn)] = ob.q[i];
            }
        }
        redg[tid] = s;

        // LoRA mid partials
        float pj[16];
        #pragma unroll
        for (int j = 0; j < 16; ++j) {
            const float4* ap = (const float4*)(loraA_l + (size_t)j * IN_F + tid * 16);
            float ps = 0.f;
            #pragma unroll
            for (int i = 0; i < 4; ++i) {
                float4 a = ap[i];
                ps += a.x * xv[i].x + a.y * xv[i].y + a.z * xv[i].z + a.w * xv[i].w;
            }
            pj[j] = ps;
        }
        #pragma unroll
        for (int j = 0; j < 16; ++j) {
            #pragma unroll
            for (int off = 32; off; off >>= 1) pj[j] += __shfl_down(pj[j], off);
        }
        if (lane == 0) {
            #pragma unroll
            for (int j = 0; j < 16; ++j) redm[wv][j] = pj[j];
        }
        __syncthreads();
        if (tid < NG) {
            float g = 0.f;
            #pragma unroll
            for (int i = 0; i < 8; ++i) g += redg[tid * 8 + i];
            xsumT[tid * TOKENS + t] = g;
        }
        if (tid < 16)
            midT[tid * TOKENS + t] = redm[0][tid] + redm[1][tid] + redm[2][tid] + redm[3][tid];
    }
}

// ---------------------------------------------------------------------------
// K2: out[t][o] = LORA_SCALE * sum_j midT[j][t] * loraB[o][j]
// Pre-initializes out (poisoned by harness) before K3's split-K atomics.
// ---------------------------------------------------------------------------
__global__ __launch_bounds__(256) void lora_out_kernel(
        const float* __restrict__ midT,
        const float* __restrict__ loraB,
        float* __restrict__ out) {
    const int gid = blockIdx.x * 256 + threadIdx.x;
    const int t = gid / OUT_F;
    const int o = gid - t * OUT_F;
    const float4* b4 = (const float4*)(loraB + (size_t)o * RANK);
    float s = 0.f;
    #pragma unroll
    for (int i = 0; i < 4; ++i) {
        float4 b = b4[i];
        s += b.x * midT[(i * 4 + 0) * TOKENS + t];
        s += b.y * midT[(i * 4 + 1) * TOKENS + t];
        s += b.z * midT[(i * 4 + 2) * TOKENS + t];
        s += b.w * midT[(i * 4 + 3) * TOKENS + t];
    }
    out[gid] = s * LORA_SCALE;
}

// ---------------------------------------------------------------------------
// K3: GPTQ-dequant GEMM, split-K=4, zero LDS / zero barriers (R2 structure).
// DIAGNOSTIC: K-loop repeated REP_MAIN times (opaque-zero pointers), acc
// scaled by exact 1/REP_MAIN before the atomic combine.
// ---------------------------------------------------------------------------
#define LOADG(st, g) do {                                                       \
    _Pragma("unroll")                                                           \
    for (int mt = 0; mt < 2; ++mt)                                              \
        _Pragma("unroll")                                                       \
        for (int ks = 0; ks < 4; ++ks)                                          \
            A[st][mt * 4 + ks] =                                                \
                xf4_l[(size_t)(((mh * 2 + mt) * 128 + (g) * 4 + ks) * 64) + lane];\
    _Pragma("unroll")                                                           \
    for (int ks = 0; ks < 4; ++ks)                                              \
        _Pragma("unroll")                                                       \
        for (int nh = 0; nh < 2; ++nh)                                          \
            B[st][ks * 2 + nh] =                                                \
                qwc_l[(size_t)((g) * 16 + ks * 4 + quad) * OUT_F + nh * 16];    \
    _Pragma("unroll")                                                           \
    for (int mt = 0; mt < 2; ++mt)                                              \
        XS[st][mt] = *(const float4*)(xsumT_l + (g) * 64 +                      \
                                      (mh * 2 + mt) * 16 + quad * 4);           \
    _Pragma("unroll")                                                           \
    for (int nh = 0; nh < 2; ++nh) {                                            \
        S[st][nh] = scales_l[(size_t)(g) * OUT_F + col0 + nh * 16 + n];         \
        Z[st][nh] = qz_l[(size_t)(g) * ZCOLS + ((col0 + nh * 16 + n) >> 3)];    \
    }                                                                           \
} while (0)

#define COMPUTEG(st) do {                                                       \
    float4v accg[2][2];                                                         \
    _Pragma("unroll")                                                           \
    for (int mt = 0; mt < 2; ++mt)                                              \
        _Pragma("unroll")                                                       \
        for (int nh = 0; nh < 2; ++nh)                                          \
            accg[mt][nh] = (float4v){0.f, 0.f, 0.f, 0.f};                       \
    _Pragma("unroll")                                                           \
    for (int ks = 0; ks < 4; ++ks) {                                            \
        union { uint4 u; short8 s; } af0, af1;                                  \
        af0.u = A[st][ks];                                                      \
        af1.u = A[st][4 + ks];                                                  \
        _Pragma("unroll")                                                       \
        for (int nh = 0; nh < 2; ++nh) {                                        \
            uint32_t q  = B[st][ks * 2 + nh];                                   \
            uint32_t lo = q & 0x0F0F0F0Fu;                                      \
            uint32_t hi = (q >> 4) & 0x0F0F0F0Fu;                               \
            union { uint32_t u32[4]; short8 s8; } bf;                           \
            _Pragma("unroll")                                                   \
            for (int i = 0; i < 4; ++i)                                         \
                bf.u32[i] = __builtin_amdgcn_perm(hi, lo,                       \
                                0x0C040C00u + i * 0x00010001u) | 0x43004300u;   \
            accg[0][nh] = __builtin_amdgcn_mfma_f32_16x16x32_bf16(af0.s, bf.s8, \
                                                            accg[0][nh], 0, 0, 0);\
            accg[1][nh] = __builtin_amdgcn_mfma_f32_16x16x32_bf16(af1.s, bf.s8, \
                                                            accg[1][nh], 0, 0, 0);\
        }                                                                       \
    }                                                                           \
    _Pragma("unroll")                                                           \
    for (int nh = 0; nh < 2; ++nh) {                                            \
        const float zoff = (float)(((Z[st][nh] >>                               \
                        (((col0 + nh * 16 + n) & 7) * 4)) & 0xFu) + 129u);      \
        const float scl = S[st][nh];                                            \
        _Pragma("unroll")                                                       \
        for (int mt = 0; mt < 2; ++mt) {                                        \
            const float xr[4] = {XS[st][mt].x, XS[st][mt].y,                    \
                                 XS[st][mt].z, XS[st][mt].w};                   \
            _Pragma("unroll")                                                   \
            for (int r = 0; r < 4; ++r)                                         \
                acc[mt][nh][r] = fmaf(scl, fmaf(-zoff, xr[r],                   \
                                      accg[mt][nh][r]), acc[mt][nh][r]);        \
        }                                                                       \
    }                                                                           \
} while (0)

__global__ __launch_bounds__(256, 3) void main_kernel(
        const uint32_t* __restrict__ qw,
        const uint32_t* __restrict__ qz,
        const float* __restrict__ scales,
        const uint4* __restrict__ xf4,
        const float* __restrict__ xsumT,
        float* __restrict__ out) {
    const int tid  = threadIdx.x;
    const int wv   = tid >> 6;
    const int lane = tid & 63;
    const int n    = lane & 15;
    const int quad = lane >> 4;
    const int mh   = wv & 1;               // M-half: tiles {2mh, 2mh+1}
    const int cs   = wv >> 1;              // col-slice within block
    const int colblk = blockIdx.x >> 2;
    const int kseg   = blockIdx.x & 3;
    const int col0   = colblk * 64 + cs * 32;
    const int g0     = kseg * 8;

    float4v acc[2][2];
    #pragma unroll
    for (int mt = 0; mt < 2; ++mt)
        #pragma unroll
        for (int nh = 0; nh < 2; ++nh)
            acc[mt][nh] = (float4v){0.f, 0.f, 0.f, 0.f};

    #pragma unroll 1
    for (int rep = 0; rep < REP_MAIN; ++rep) {
        int zero;
        asm volatile("v_mov_b32 %0, 0" : "=v"(zero));   // opaque 0: no LICM
        const uint32_t* qwc_l    = qw + col0 + n + zero;
        const uint32_t* qz_l     = qz + zero;
        const float*    scales_l = scales + zero;
        const uint4*    xf4_l    = xf4 + zero;
        const float*    xsumT_l  = xsumT + zero;

        uint4    A[2][8];
        uint32_t B[2][8];
        float4   XS[2][2];
        float    S[2][2];
        uint32_t Z[2][2];

        LOADG(0, g0);
        LOADG(1, g0 + 1);
        #pragma unroll
        for (int gi = 0; gi < 8; ++gi) {
            const int st = gi & 1;
            COMPUTEG(st);
            int gl = gi + 2; if (gl > 7) gl = 7;   // clamped tail refill (unused)
            LOADG(st, g0 + gl);
        }
    }

    // split-K combine: scale by exact 1/REP_MAIN, 4 partials per element
    const float inv = 1.0f / (float)REP_MAIN;
    #pragma unroll
    for (int mt = 0; mt < 2; ++mt)
        #pragma unroll
        for (int nh = 0; nh < 2; ++nh)
            #pragma unroll
            for (int r = 0; r < 4; ++r) {
                const int t = (mh * 2 + mt) * 16 + quad * 4 + r;
                atomicAdd(out + (size_t)t * OUT_F + col0 + nh * 16 + n,
                          acc[mt][nh][r] * inv);
            }
}

// ---------------------------------------------------------------------------
extern "C" void kernel_launch(void* const* d_in, const int* in_sizes, int n_in,
                              void* d_out, int out_size, void* d_ws, size_t ws_size,
                              hipStream_t stream) {
    const float*    x      = (const float*)d_in[0];
    const uint32_t* qw     = (const uint32_t*)d_in[1];
    const uint32_t* qz     = (const uint32_t*)d_in[2];
    const float*    scales = (const float*)d_in[3];
    const float*    loraA  = (const float*)d_in[4];
    const float*    loraB  = (const float*)d_in[5];
    float* out = (float*)d_out;

    // ws layout: xf bf16-fragments [4][128][64] uint4 (512 KB) | xsumT | midT
    uint4* xf4   = (uint4*)d_ws;
    float* xsumT = (float*)((char*)d_ws + (size_t)TOKENS * IN_F * 2);
    float* midT  = xsumT + NG * TOKENS;

    prep_kernel<<<TOKENS, 256, 0, stream>>>(x, loraA, xf4, xsumT, midT);
    lora_out_kernel<<<(TOKENS * OUT_F) / 256, 256, 0, stream>>>(midT, loraB, out);
    main_kernel<<<(OUT_F / 64) * 4, 256, 0, stream>>>(qw, qz, scales, xf4, xsumT, out);
}

// Round 8
// 113.643 us; speedup vs baseline: 10.5239x; 10.5239x over previous
//
#include <hip/hip_runtime.h>
#include <stdint.h>

// Problem constants (fixed by setup_inputs)
#define TOKENS 64
#define IN_F   4096
#define OUT_F  11008
#define RANK   16
#define GS     128
#define NG     32
#define ZCOLS  (OUT_F / 8)
#define LORA_SCALE 2.0f

using short8  = __attribute__((ext_vector_type(8))) short;
using float4v = __attribute__((ext_vector_type(4))) float;

typedef __attribute__((address_space(3))) uint32_t       lds_u32_t;
typedef __attribute__((address_space(1))) const uint32_t glb_u32_t;

// round-to-nearest-even fp32 -> bf16 bits; also returns the rounded-back fp32
static __device__ inline uint16_t f2bf(float f, float* back) {
    uint32_t u = __float_as_uint(f);
    uint32_t r = (u + 0x7FFFu + ((u >> 16) & 1u)) >> 16;
    *back = __uint_as_float(r << 16);
    return (uint16_t)r;
}

// ---------------------------------------------------------------------------
// K1: per token t (64 blocks):
//   xf (MFMA-fragment order) = bf16(x)  — xf4[(mt*128 + kchunk)*64 + quad*16 + n]
//   xsumT[g][t] = sum over group g of bf16-rounded x   (GPTQ zero fold)
//   midT[j][t]  = sum_k x[t][k] * lora_A[j][k]         (fp32 LoRA mid)
// ---------------------------------------------------------------------------
__global__ __launch_bounds__(256) void prep_kernel(
        const float* __restrict__ x,
        const float* __restrict__ loraA,
        uint4* __restrict__ xf4,
        float* __restrict__ xsumT,
        float* __restrict__ midT) {
    __shared__ float redg[256];
    __shared__ float redm[4][16];
    const int t    = blockIdx.x;
    const int tid  = threadIdx.x;
    const int lane = tid & 63;
    const int wv   = tid >> 6;

    float4 xv[4];
    const float4* xp = (const float4*)(x + (size_t)t * IN_F + tid * 16);
    #pragma unroll
    for (int i = 0; i < 4; ++i) xv[i] = xp[i];

    union { uint16_t u[16]; uint4 q[2]; } ob;
    float s = 0.f;
    #pragma unroll
    for (int i = 0; i < 4; ++i) {
        float b;
        ob.u[i * 4 + 0] = f2bf(xv[i].x, &b); s += b;
        ob.u[i * 4 + 1] = f2bf(xv[i].y, &b); s += b;
        ob.u[i * 4 + 2] = f2bf(xv[i].z, &b); s += b;
        ob.u[i * 4 + 3] = f2bf(xv[i].w, &b); s += b;
    }
    // scatter into fragment order
    {
        const int mm = t >> 4, nn = t & 15;
        const int kchunk = tid >> 1;
        #pragma unroll
        for (int i = 0; i < 2; ++i) {
            const int qd = (tid * 2 + i) & 3;
            xf4[(size_t)((mm * 128 + kchunk) * 64 + qd * 16 + nn)] = ob.q[i];
        }
    }
    redg[tid] = s;

    // LoRA mid partials
    float pj[16];
    #pragma unroll
    for (int j = 0; j < 16; ++j) {
        const float4* ap = (const float4*)(loraA + (size_t)j * IN_F + tid * 16);
        float ps = 0.f;
        #pragma unroll
        for (int i = 0; i < 4; ++i) {
            float4 a = ap[i];
            ps += a.x * xv[i].x + a.y * xv[i].y + a.z * xv[i].z + a.w * xv[i].w;
        }
        pj[j] = ps;
    }
    #pragma unroll
    for (int j = 0; j < 16; ++j) {
        #pragma unroll
        for (int off = 32; off; off >>= 1) pj[j] += __shfl_down(pj[j], off);
    }
    if (lane == 0) {
        #pragma unroll
        for (int j = 0; j < 16; ++j) redm[wv][j] = pj[j];
    }
    __syncthreads();
    if (tid < NG) {
        float g = 0.f;
        #pragma unroll
        for (int i = 0; i < 8; ++i) g += redg[tid * 8 + i];
        xsumT[tid * TOKENS + t] = g;
    }
    if (tid < 16)
        midT[tid * TOKENS + t] = redm[0][tid] + redm[1][tid] + redm[2][tid] + redm[3][tid];
}

// ---------------------------------------------------------------------------
// K2: out[t][o] = LORA_SCALE * sum_j midT[j][t] * loraB[o][j]
// Pre-initializes out (poisoned by harness) before K3's split-K atomics.
// ---------------------------------------------------------------------------
__global__ __launch_bounds__(256) void lora_out_kernel(
        const float* __restrict__ midT,
        const float* __restrict__ loraB,
        float* __restrict__ out) {
    const int gid = blockIdx.x * 256 + threadIdx.x;
    const int t = gid / OUT_F;
    const int o = gid - t * OUT_F;
    const float4* b4 = (const float4*)(loraB + (size_t)o * RANK);
    float s = 0.f;
    #pragma unroll
    for (int i = 0; i < 4; ++i) {
        float4 b = b4[i];
        s += b.x * midT[(i * 4 + 0) * TOKENS + t];
        s += b.y * midT[(i * 4 + 1) * TOKENS + t];
        s += b.z * midT[(i * 4 + 2) * TOKENS + t];
        s += b.w * midT[(i * 4 + 3) * TOKENS + t];
    }
    out[gid] = s * LORA_SCALE;
}

// ---------------------------------------------------------------------------
// K3: GPTQ-dequant GEMM, split-K=4, R2 grid/roles, LDS-staged B.
// R7 diagnosis: old K-loop was latency-bound (one load in flight; VGPR=84
// collapsed the A[2][8] ring; MfmaUtil 5%, 13.7k cy/group). Fix:
//  - qw tile (16 rows x 64 cols = 4 KB) staged per group via
//    __builtin_amdgcn_global_load_lds width=16 (1 instr/thread, coalesced,
//    zero VGPR), double-buffered; __syncthreads() drains stage (barrier
//    implies vmcnt(0)) and protects buffer swap.
//  - A/XS/S/Z: direct per-group loads (xf4/scales L2-resident), no ring
//    -> register pressure drops, compiler can schedule real MLP.
// Dequant math, atomic combine, grid = 172 colblk x 4 kseg unchanged.
// ---------------------------------------------------------------------------
__global__ __launch_bounds__(256, 2) void main_kernel(
        const uint32_t* __restrict__ qw,
        const uint32_t* __restrict__ qz,
        const float* __restrict__ scales,
        const uint4* __restrict__ xf4,
        const float* __restrict__ xsumT,
        float* __restrict__ out) {
    __shared__ uint32_t bq[2][16 * 64];   // [buf][row*64 + dword], 4 KB each
    const int tid  = threadIdx.x;
    const int wv   = tid >> 6;
    const int lane = tid & 63;
    const int n    = lane & 15;
    const int quad = lane >> 4;
    const int mh   = wv & 1;               // M-half: tiles {2mh, 2mh+1}
    const int cs   = wv >> 1;              // col-slice within block
    const int colblk = blockIdx.x >> 2;
    const int kseg   = blockIdx.x & 3;
    const int blkcol0 = colblk * 64;       // block col base (staging)
    const int col0    = blkcol0 + cs * 32; // wave col base
    const int g0      = kseg * 8;

    // staging source: thread stages row (tid>>4), dwords (tid&15)*4..+3
    const uint32_t* qsrc = qw + (size_t)(g0 * 16 + (tid >> 4)) * OUT_F
                              + blkcol0 + (tid & 15) * 4;
    const size_t gstride = (size_t)16 * OUT_F;   // dwords per group of rows

    float4v acc[2][2];
    #pragma unroll
    for (int mt = 0; mt < 2; ++mt)
        #pragma unroll
        for (int nh = 0; nh < 2; ++nh)
            acc[mt][nh] = (float4v){0.f, 0.f, 0.f, 0.f};

    // prologue: stage group g0 into buf 0
    __builtin_amdgcn_global_load_lds((glb_u32_t*)qsrc,
                                     (lds_u32_t*)&bq[0][wv * 256], 16, 0, 0);
    __syncthreads();   // drains vmcnt -> tile 0 resident

    #pragma unroll
    for (int gi = 0; gi < 8; ++gi) {
        const int cur = gi & 1;
        const int g   = g0 + gi;

        // direct loads for this group (L2-resident; issued before stage so
        // the compiler's counted vmcnt wait for A leaves the stage in flight)
        uint4 A[8];
        #pragma unroll
        for (int mt = 0; mt < 2; ++mt)
            #pragma unroll
            for (int ks = 0; ks < 4; ++ks)
                A[mt * 4 + ks] =
                    xf4[(size_t)(((mh * 2 + mt) * 128 + g * 4 + ks) * 64) + lane];
        float4 XS[2];
        #pragma unroll
        for (int mt = 0; mt < 2; ++mt)
            XS[mt] = *(const float4*)(xsumT + g * 64 + (mh * 2 + mt) * 16 + quad * 4);
        float S[2]; uint32_t Z[2];
        #pragma unroll
        for (int nh = 0; nh < 2; ++nh) {
            S[nh] = scales[(size_t)g * OUT_F + col0 + nh * 16 + n];
            Z[nh] = qz[(size_t)g * ZCOLS + ((col0 + nh * 16 + n) >> 3)];
        }

        // async-stage next group into the other buffer
        if (gi < 7)
            __builtin_amdgcn_global_load_lds(
                (glb_u32_t*)(qsrc + (size_t)(gi + 1) * gstride),
                (lds_u32_t*)&bq[cur ^ 1][wv * 256], 16, 0, 0);

        // B words from LDS: row = ks*4+quad, dword-in-row = cs*32+nh*16+n
        uint32_t Bw[8];
        #pragma unroll
        for (int ks = 0; ks < 4; ++ks)
            #pragma unroll
            for (int nh = 0; nh < 2; ++nh)
                Bw[ks * 2 + nh] =
                    bq[cur][(ks * 4 + quad) * 64 + cs * 32 + nh * 16 + n];

        // dequant + MFMA (identical math to R2)
        float4v accg[2][2];
        #pragma unroll
        for (int mt = 0; mt < 2; ++mt)
            #pragma unroll
            for (int nh = 0; nh < 2; ++nh)
                accg[mt][nh] = (float4v){0.f, 0.f, 0.f, 0.f};
        #pragma unroll
        for (int ks = 0; ks < 4; ++ks) {
            union { uint4 u; short8 s; } af0, af1;
            af0.u = A[ks];
            af1.u = A[4 + ks];
            #pragma unroll
            for (int nh = 0; nh < 2; ++nh) {
                uint32_t q  = Bw[ks * 2 + nh];
                uint32_t lo = q & 0x0F0F0F0Fu;
                uint32_t hi = (q >> 4) & 0x0F0F0F0Fu;
                union { uint32_t u32[4]; short8 s8; } bf;
                #pragma unroll
                for (int i = 0; i < 4; ++i)
                    bf.u32[i] = __builtin_amdgcn_perm(hi, lo,
                                    0x0C040C00u + i * 0x00010001u) | 0x43004300u;
                accg[0][nh] = __builtin_amdgcn_mfma_f32_16x16x32_bf16(
                                    af0.s, bf.s8, accg[0][nh], 0, 0, 0);
                accg[1][nh] = __builtin_amdgcn_mfma_f32_16x16x32_bf16(
                                    af1.s, bf.s8, accg[1][nh], 0, 0, 0);
            }
        }
        #pragma unroll
        for (int nh = 0; nh < 2; ++nh) {
            const float zoff =
                (float)(((Z[nh] >> (((col0 + nh * 16 + n) & 7) * 4)) & 0xFu) + 129u);
            const float scl = S[nh];
            #pragma unroll
            for (int mt = 0; mt < 2; ++mt) {
                const float xr[4] = {XS[mt].x, XS[mt].y, XS[mt].z, XS[mt].w};
                #pragma unroll
                for (int r = 0; r < 4; ++r)
                    acc[mt][nh][r] = fmaf(scl, fmaf(-zoff, xr[r], accg[mt][nh][r]),
                                          acc[mt][nh][r]);
            }
        }

        // barrier: (a) all waves done reading bq[cur] before it is restaged,
        // (b) implied vmcnt(0) drain -> next tile resident for gi+1
        __syncthreads();
    }

    // split-K combine: 4 partials per output element (shown ~free in R7)
    #pragma unroll
    for (int mt = 0; mt < 2; ++mt)
        #pragma unroll
        for (int nh = 0; nh < 2; ++nh)
            #pragma unroll
            for (int r = 0; r < 4; ++r) {
                const int t = (mh * 2 + mt) * 16 + quad * 4 + r;
                atomicAdd(out + (size_t)t * OUT_F + col0 + nh * 16 + n,
                          acc[mt][nh][r]);
            }
}

// ---------------------------------------------------------------------------
extern "C" void kernel_launch(void* const* d_in, const int* in_sizes, int n_in,
                              void* d_out, int out_size, void* d_ws, size_t ws_size,
                              hipStream_t stream) {
    const float*    x      = (const float*)d_in[0];
    const uint32_t* qw     = (const uint32_t*)d_in[1];
    const uint32_t* qz     = (const uint32_t*)d_in[2];
    const float*    scales = (const float*)d_in[3];
    const float*    loraA  = (const float*)d_in[4];
    const float*    loraB  = (const float*)d_in[5];
    float* out = (float*)d_out;

    // ws layout: xf bf16-fragments [4][128][64] uint4 (512 KB) | xsumT | midT
    uint4* xf4   = (uint4*)d_ws;
    float* xsumT = (float*)((char*)d_ws + (size_t)TOKENS * IN_F * 2);
    float* midT  = xsumT + NG * TOKENS;

    prep_kernel<<<TOKENS, 256, 0, stream>>>(x, loraA, xf4, xsumT, midT);
    lora_out_kernel<<<(TOKENS * OUT_F) / 256, 256, 0, stream>>>(midT, loraB, out);
    main_kernel<<<(OUT_F / 64) * 4, 256, 0, stream>>>(qw, qz, scales, xf4, xsumT, out);
}

// Round 9
// 106.950 us; speedup vs baseline: 11.1825x; 1.0626x over previous
//
#include <hip/hip_runtime.h>
#include <stdint.h>

// Problem constants (fixed by setup_inputs)
#define TOKENS 64
#define IN_F   4096
#define OUT_F  11008
#define RANK   16
#define GS     128
#define NG     32
#define ZCOLS  (OUT_F / 8)
#define LORA_SCALE 2.0f

using short8  = __attribute__((ext_vector_type(8))) short;
using float4v = __attribute__((ext_vector_type(4))) float;

// round-to-nearest-even fp32 -> bf16 bits; also returns the rounded-back fp32
static __device__ inline uint16_t f2bf(float f, float* back) {
    uint32_t u = __float_as_uint(f);
    uint32_t r = (u + 0x7FFFu + ((u >> 16) & 1u)) >> 16;
    *back = __uint_as_float(r << 16);
    return (uint16_t)r;
}

// ---------------------------------------------------------------------------
// K1: per token t (64 blocks):
//   xf (MFMA-fragment order) = bf16(x)  — xf4[(mt*128 + kchunk)*64 + quad*16 + n]
//   xsumT[g][t] = sum over group g of bf16-rounded x   (GPTQ zero fold)
//   midT[j][t]  = sum_k x[t][k] * lora_A[j][k]         (fp32 LoRA mid)
// ---------------------------------------------------------------------------
__global__ __launch_bounds__(256) void prep_kernel(
        const float* __restrict__ x,
        const float* __restrict__ loraA,
        uint4* __restrict__ xf4,
        float* __restrict__ xsumT,
        float* __restrict__ midT) {
    __shared__ float redg[256];
    __shared__ float redm[4][16];
    const int t    = blockIdx.x;
    const int tid  = threadIdx.x;
    const int lane = tid & 63;
    const int wv   = tid >> 6;

    float4 xv[4];
    const float4* xp = (const float4*)(x + (size_t)t * IN_F + tid * 16);
    #pragma unroll
    for (int i = 0; i < 4; ++i) xv[i] = xp[i];

    union { uint16_t u[16]; uint4 q[2]; } ob;
    float s = 0.f;
    #pragma unroll
    for (int i = 0; i < 4; ++i) {
        float b;
        ob.u[i * 4 + 0] = f2bf(xv[i].x, &b); s += b;
        ob.u[i * 4 + 1] = f2bf(xv[i].y, &b); s += b;
        ob.u[i * 4 + 2] = f2bf(xv[i].z, &b); s += b;
        ob.u[i * 4 + 3] = f2bf(xv[i].w, &b); s += b;
    }
    // scatter into fragment order
    {
        const int mm = t >> 4, nn = t & 15;
        const int kchunk = tid >> 1;
        #pragma unroll
        for (int i = 0; i < 2; ++i) {
            const int qd = (tid * 2 + i) & 3;
            xf4[(size_t)((mm * 128 + kchunk) * 64 + qd * 16 + nn)] = ob.q[i];
        }
    }
    redg[tid] = s;

    // LoRA mid partials
    float pj[16];
    #pragma unroll
    for (int j = 0; j < 16; ++j) {
        const float4* ap = (const float4*)(loraA + (size_t)j * IN_F + tid * 16);
        float ps = 0.f;
        #pragma unroll
        for (int i = 0; i < 4; ++i) {
            float4 a = ap[i];
            ps += a.x * xv[i].x + a.y * xv[i].y + a.z * xv[i].z + a.w * xv[i].w;
        }
        pj[j] = ps;
    }
    #pragma unroll
    for (int j = 0; j < 16; ++j) {
        #pragma unroll
        for (int off = 32; off; off >>= 1) pj[j] += __shfl_down(pj[j], off);
    }
    if (lane == 0) {
        #pragma unroll
        for (int j = 0; j < 16; ++j) redm[wv][j] = pj[j];
    }
    __syncthreads();
    if (tid < NG) {
        float g = 0.f;
        #pragma unroll
        for (int i = 0; i < 8; ++i) g += redg[tid * 8 + i];
        xsumT[tid * TOKENS + t] = g;
    }
    if (tid < 16)
        midT[tid * TOKENS + t] = redm[0][tid] + redm[1][tid] + redm[2][tid] + redm[3][tid];
}

// ---------------------------------------------------------------------------
// K2: out[t][o] = LORA_SCALE * sum_j midT[j][t] * loraB[o][j]
// Pre-initializes out (poisoned by harness) before K3's split-K atomics.
// ---------------------------------------------------------------------------
__global__ __launch_bounds__(256) void lora_out_kernel(
        const float* __restrict__ midT,
        const float* __restrict__ loraB,
        float* __restrict__ out) {
    const int gid = blockIdx.x * 256 + threadIdx.x;
    const int t = gid / OUT_F;
    const int o = gid - t * OUT_F;
    const float4* b4 = (const float4*)(loraB + (size_t)o * RANK);
    float s = 0.f;
    #pragma unroll
    for (int i = 0; i < 4; ++i) {
        float4 b = b4[i];
        s += b.x * midT[(i * 4 + 0) * TOKENS + t];
        s += b.y * midT[(i * 4 + 1) * TOKENS + t];
        s += b.z * midT[(i * 4 + 2) * TOKENS + t];
        s += b.w * midT[(i * 4 + 3) * TOKENS + t];
    }
    out[gid] = s * LORA_SCALE;
}

// ---------------------------------------------------------------------------
// K3: GPTQ-dequant GEMM, split-K=4, zero LDS / zero barriers (R2 structure).
// R8 diagnosis: __launch_bounds__(256,3) sets only a MIN waves/EU; LLVM
// squeezed VGPRs to 84 (6 waves/SIMD target) on a grid that can only use
// 2.7 — serializing all K-loop loads and spilling the ring to scratch
// (R7 PMC: WRITE 66 MB/rep from a store-free loop, MfmaUtil 5%).
// FIX: amdgpu_waves_per_eu(3,3) pins the allocator at 3 waves/SIMD
// (170-VGPR budget) so the depth-2 ring stays in registers and ~22 loads
// per wave stay in flight. Everything else byte-identical to R2.
// ---------------------------------------------------------------------------
#define LOADG(st, g) do {                                                       \
    _Pragma("unroll")                                                           \
    for (int mt = 0; mt < 2; ++mt)                                              \
        _Pragma("unroll")                                                       \
        for (int ks = 0; ks < 4; ++ks)                                          \
            A[st][mt * 4 + ks] =                                                \
                xf4[(size_t)(((mh * 2 + mt) * 128 + (g) * 4 + ks) * 64) + lane];\
    _Pragma("unroll")                                                           \
    for (int ks = 0; ks < 4; ++ks)                                              \
        _Pragma("unroll")                                                       \
        for (int nh = 0; nh < 2; ++nh)                                          \
            B[st][ks * 2 + nh] =                                                \
                qwc[(size_t)((g) * 16 + ks * 4 + quad) * OUT_F + nh * 16];      \
    _Pragma("unroll")                                                           \
    for (int mt = 0; mt < 2; ++mt)                                              \
        XS[st][mt] = *(const float4*)(xsumT + (g) * 64 +                        \
                                      (mh * 2 + mt) * 16 + quad * 4);           \
    _Pragma("unroll")                                                           \
    for (int nh = 0; nh < 2; ++nh) {                                            \
        S[st][nh] = scales[(size_t)(g) * OUT_F + col0 + nh * 16 + n];           \
        Z[st][nh] = qz[(size_t)(g) * ZCOLS + ((col0 + nh * 16 + n) >> 3)];      \
    }                                                                           \
} while (0)

#define COMPUTEG(st) do {                                                       \
    float4v accg[2][2];                                                         \
    _Pragma("unroll")                                                           \
    for (int mt = 0; mt < 2; ++mt)                                              \
        _Pragma("unroll")                                                       \
        for (int nh = 0; nh < 2; ++nh)                                          \
            accg[mt][nh] = (float4v){0.f, 0.f, 0.f, 0.f};                       \
    _Pragma("unroll")                                                           \
    for (int ks = 0; ks < 4; ++ks) {                                            \
        union { uint4 u; short8 s; } af0, af1;                                  \
        af0.u = A[st][ks];                                                      \
        af1.u = A[st][4 + ks];                                                  \
        _Pragma("unroll")                                                       \
        for (int nh = 0; nh < 2; ++nh) {                                        \
            uint32_t q  = B[st][ks * 2 + nh];                                   \
            uint32_t lo = q & 0x0F0F0F0Fu;                                      \
            uint32_t hi = (q >> 4) & 0x0F0F0F0Fu;                               \
            union { uint32_t u32[4]; short8 s8; } bf;                           \
            _Pragma("unroll")                                                   \
            for (int i = 0; i < 4; ++i)                                         \
                bf.u32[i] = __builtin_amdgcn_perm(hi, lo,                       \
                                0x0C040C00u + i * 0x00010001u) | 0x43004300u;   \
            accg[0][nh] = __builtin_amdgcn_mfma_f32_16x16x32_bf16(af0.s, bf.s8, \
                                                            accg[0][nh], 0, 0, 0);\
            accg[1][nh] = __builtin_amdgcn_mfma_f32_16x16x32_bf16(af1.s, bf.s8, \
                                                            accg[1][nh], 0, 0, 0);\
        }                                                                       \
    }                                                                           \
    _Pragma("unroll")                                                           \
    for (int nh = 0; nh < 2; ++nh) {                                            \
        const float zoff = (float)(((Z[st][nh] >>                               \
                        (((col0 + nh * 16 + n) & 7) * 4)) & 0xFu) + 129u);      \
        const float scl = S[st][nh];                                            \
        _Pragma("unroll")                                                       \
        for (int mt = 0; mt < 2; ++mt) {                                        \
            const float xr[4] = {XS[st][mt].x, XS[st][mt].y,                    \
                                 XS[st][mt].z, XS[st][mt].w};                   \
            _Pragma("unroll")                                                   \
            for (int r = 0; r < 4; ++r)                                         \
                acc[mt][nh][r] = fmaf(scl, fmaf(-zoff, xr[r],                   \
                                      accg[mt][nh][r]), acc[mt][nh][r]);        \
        }                                                                       \
    }                                                                           \
} while (0)

__global__ __launch_bounds__(256)
__attribute__((amdgpu_waves_per_eu(3, 3)))
void main_kernel(
        const uint32_t* __restrict__ qw,
        const uint32_t* __restrict__ qz,
        const float* __restrict__ scales,
        const uint4* __restrict__ xf4,
        const float* __restrict__ xsumT,
        float* __restrict__ out) {
    const int tid  = threadIdx.x;
    const int wv   = tid >> 6;
    const int lane = tid & 63;
    const int n    = lane & 15;
    const int quad = lane >> 4;
    const int mh   = wv & 1;               // M-half: tiles {2mh, 2mh+1}
    const int cs   = wv >> 1;              // col-slice within block
    const int colblk = blockIdx.x >> 2;
    const int kseg   = blockIdx.x & 3;
    const int col0   = colblk * 64 + cs * 32;
    const int g0     = kseg * 8;

    const uint32_t* qwc = qw + col0 + n;

    float4v acc[2][2];
    #pragma unroll
    for (int mt = 0; mt < 2; ++mt)
        #pragma unroll
        for (int nh = 0; nh < 2; ++nh)
            acc[mt][nh] = (float4v){0.f, 0.f, 0.f, 0.f};

    uint4    A[2][8];
    uint32_t B[2][8];
    float4   XS[2][2];
    float    S[2][2];
    uint32_t Z[2][2];

    LOADG(0, g0);
    LOADG(1, g0 + 1);
    #pragma unroll
    for (int gi = 0; gi < 8; ++gi) {
        const int st = gi & 1;
        COMPUTEG(st);
        int gl = gi + 2; if (gl > 7) gl = 7;   // clamped tail refill (unused)
        LOADG(st, g0 + gl);
    }

    // split-K combine: 4 partials per output element (measured ~free in R7)
    #pragma unroll
    for (int mt = 0; mt < 2; ++mt)
        #pragma unroll
        for (int nh = 0; nh < 2; ++nh)
            #pragma unroll
            for (int r = 0; r < 4; ++r) {
                const int t = (mh * 2 + mt) * 16 + quad * 4 + r;
                atomicAdd(out + (size_t)t * OUT_F + col0 + nh * 16 + n,
                          acc[mt][nh][r]);
            }
}

// ---------------------------------------------------------------------------
extern "C" void kernel_launch(void* const* d_in, const int* in_sizes, int n_in,
                              void* d_out, int out_size, void* d_ws, size_t ws_size,
                              hipStream_t stream) {
    const float*    x      = (const float*)d_in[0];
    const uint32_t* qw     = (const uint32_t*)d_in[1];
    const uint32_t* qz     = (const uint32_t*)d_in[2];
    const float*    scales = (const float*)d_in[3];
    const float*    loraA  = (const float*)d_in[4];
    const float*    loraB  = (const float*)d_in[5];
    float* out = (float*)d_out;

    // ws layout: xf bf16-fragments [4][128][64] uint4 (512 KB) | xsumT | midT
    uint4* xf4   = (uint4*)d_ws;
    float* xsumT = (float*)((char*)d_ws + (size_t)TOKENS * IN_F * 2);
    float* midT  = xsumT + NG * TOKENS;

    prep_kernel<<<TOKENS, 256, 0, stream>>>(x, loraA, xf4, xsumT, midT);
    lora_out_kernel<<<(TOKENS * OUT_F) / 256, 256, 0, stream>>>(midT, loraB, out);
    main_kernel<<<(OUT_F / 64) * 4, 256, 0, stream>>>(qw, qz, scales, xf4, xsumT, out);
}